// Round 6
// baseline (5302.484 us; speedup 1.0000x reference)
//
#include <hip/hip_runtime.h>

#define M_DIM 16384
#define K_DIM 768
#define N_DIM 12288
#define TOPK  32

__device__ __forceinline__ unsigned f2u(float f) {
  union { float f; unsigned u; } v; v.f = f; return v.u;
}
__device__ __forceinline__ float u2f(unsigned u) {
  union { unsigned u; float f; } v; v.u = u; return v.f;
}

// ---------------------------------------------------------------------------
// Kernel 1: z = x @ enc_w^T + enc_b  (all fp32, VALU)
// A = x (M x K), B = enc_w (N x K), both K-contiguous row-major.
// 128x128 tile, 256 threads (16x16), 8x8 outputs/thread, K slabs of 32.
// ---------------------------------------------------------------------------
__global__ void TopKSparseAutoencoder_51917564674099_kernel(
    const float* A, const float* B, const float* bias, float* Z)
{
  __shared__ float As[32][132];   // [k][m], row padded to 132 (16B-aligned rows)
  __shared__ float Bs[32][132];   // [k][n]

  const int tx = (int)threadIdx.x;          // 0..15
  const int ty = (int)threadIdx.y;          // 0..15
  const int t  = ty * 16 + tx;              // 0..255
  const int n0 = (int)blockIdx.x * 128;
  const int m0 = (int)blockIdx.y * 128;

  // staging: thread t loads 16 contiguous floats of row r, k-half h
  const int r = t >> 1;                     // 0..127
  const int h = (t & 1) * 16;               // 0 or 16

  float c[8][8];
#pragma unroll
  for (int i = 0; i < 8; ++i)
#pragma unroll
    for (int j = 0; j < 8; ++j) c[i][j] = 0.0f;

  for (int k0 = 0; k0 < K_DIM; k0 += 32) {
    const float* pa = A + (size_t)(m0 + r) * K_DIM + k0 + h;
    const float* pb = B + (size_t)(n0 + r) * K_DIM + k0 + h;
    float fa[16], fb[16];
#pragma unroll
    for (int j = 0; j < 16; ++j) fa[j] = pa[j];
#pragma unroll
    for (int j = 0; j < 16; ++j) fb[j] = pb[j];
#pragma unroll
    for (int j = 0; j < 16; ++j) As[h + j][r] = fa[j];
#pragma unroll
    for (int j = 0; j < 16; ++j) Bs[h + j][r] = fb[j];
    __syncthreads();

    for (int kk = 0; kk < 32; ++kk) {
      float av[8], bv[8];
#pragma unroll
      for (int i = 0; i < 8; ++i) av[i] = As[kk][ty * 8 + i];
#pragma unroll
      for (int j = 0; j < 8; ++j) bv[j] = Bs[kk][tx * 8 + j];
#pragma unroll
      for (int i = 0; i < 8; ++i)
#pragma unroll
        for (int j = 0; j < 8; ++j) c[i][j] += av[i] * bv[j];
    }
    __syncthreads();
  }

#pragma unroll
  for (int j = 0; j < 8; ++j) {
    const int col = n0 + tx * 8 + j;
    const float bb = bias[col];
#pragma unroll
    for (int i = 0; i < 8; ++i)
      Z[(size_t)(m0 + ty * 8 + i) * N_DIM + col] = c[i][j] + bb;
  }
}

// ---------------------------------------------------------------------------
// Kernel 2: dec_w (768 x 12288) -> dec_wT (12288 x 768), fp32
// ---------------------------------------------------------------------------
__global__ void transpose_decw(const float* W, float* WT)
{
  __shared__ float tile[32][33];
  const int bx = (int)blockIdx.x;       // over N (384 tiles)
  const int by = (int)blockIdx.y;       // over K (24 tiles)
  const int tx = (int)threadIdx.x;      // 32
  const int ty = (int)threadIdx.y;      // 8
#pragma unroll
  for (int j = 0; j < 32; j += 8)
    tile[ty + j][tx] = W[(size_t)(by * 32 + ty + j) * N_DIM + bx * 32 + tx];
  __syncthreads();
#pragma unroll
  for (int j = 0; j < 32; j += 8)
    WT[(size_t)(bx * 32 + ty + j) * K_DIM + by * 32 + tx] = tile[tx][ty + j];
}

// ---------------------------------------------------------------------------
// Kernel 3: per-row EXACT top-32 threshold via 4-pass radix select on 32-bit
// order-preserving keys, relu(z - thresh) in place, compact, sparse decode.
// One 256-thread block per row.
// ---------------------------------------------------------------------------
__global__ void topk_decode(
    float* Z,          // in: raw z, out: z_sparse (M x N)
    const float* WT,   // dec_wT (N x K), valid if use_wt
    const float* DW,   // dec_w  (K x N), fallback
    const float* db,   // dec_b  (K)
    float* XR,         // x_recon (M x K)
    int use_wt)
{
  __shared__ float zrow[N_DIM];         // 48 KB
  __shared__ unsigned hist[256];
  __shared__ unsigned suf[256];
  __shared__ unsigned s_bin;
  __shared__ unsigned s_above;
  __shared__ int s_nnz;
  __shared__ int   s_col[TOPK];
  __shared__ float s_val[TOPK];

  const int row = (int)blockIdx.x;
  const int t   = (int)threadIdx.x;

  float4* zv = (float4*)(Z + (size_t)row * N_DIM);
  float4* lv = (float4*)zrow;
  for (int c = t; c < N_DIM / 4; c += 256) lv[c] = zv[c];   // coalesced 16B
  if (t == 0) s_nnz = 0;
  __syncthreads();

  // 4-pass MSB->LSB radix select for the exact 32nd-largest value.
  unsigned prefix = 0, mask = 0;
  int r = TOPK;
  for (int shift = 24; shift >= 0; shift -= 8) {
    hist[t] = 0;
    __syncthreads();
    for (int j = 0; j < N_DIM / 256; ++j) {
      unsigned u   = f2u(zrow[t + 256 * j]);
      unsigned key = u ^ (unsigned)(((int)u >> 31) | 0x80000000);
      if ((key & mask) == prefix) atomicAdd(&hist[(key >> shift) & 255u], 1u);
    }
    __syncthreads();
    suf[t] = hist[t];
    __syncthreads();
    for (int off = 1; off < 256; off <<= 1) {
      unsigned add = (t + off < 256) ? suf[t + off] : 0u;
      __syncthreads();
      suf[t] += add;
      __syncthreads();
    }
    {
      unsigned me = suf[t];
      unsigned nx = (t < 255) ? suf[t + 1] : 0u;
      if (me >= (unsigned)r && nx < (unsigned)r) { s_bin = (unsigned)t; s_above = nx; }
    }
    __syncthreads();
    prefix |= s_bin << shift;
    mask   |= 0xFFu << shift;
    r      -= (int)s_above;
    __syncthreads();
  }
  const unsigned tu = (prefix & 0x80000000u) ? (prefix ^ 0x80000000u) : ~prefix;
  const float thresh = u2f(tu);   // exact 32nd-largest z in this row

  // relu(z - thresh) in place; compact strictly-greater entries (<= 31)
  for (int j = 0; j < N_DIM / 256; ++j) {
    const int idx = t + 256 * j;
    float v = zrow[idx];
    float o = v - thresh;
    if (o > 0.0f) {
      int p = atomicAdd(&s_nnz, 1);
      if (p < TOPK) { s_col[p] = idx; s_val[p] = o; }
      zrow[idx] = o;
    } else {
      zrow[idx] = 0.0f;
    }
  }
  __syncthreads();
  for (int c = t; c < N_DIM / 4; c += 256) zv[c] = lv[c];   // z_sparse out

  // sparse decode: x_recon[row][i] = sum_j val_j * dec_w[i][col_j] + dec_b[i]
  const int nnz = (s_nnz < TOPK) ? s_nnz : TOPK;
  float a0 = 0.0f, a1 = 0.0f, a2 = 0.0f;
  if (use_wt) {
    for (int j = 0; j < nnz; ++j) {
      const float v = s_val[j];
      const float* w = WT + (size_t)s_col[j] * K_DIM;
      a0 += v * w[t];
      a1 += v * w[t + 256];
      a2 += v * w[t + 512];
    }
  } else {
    for (int j = 0; j < nnz; ++j) {
      const float v = s_val[j];
      const int col = s_col[j];
      a0 += v * DW[(size_t)(t)       * N_DIM + col];
      a1 += v * DW[(size_t)(t + 256) * N_DIM + col];
      a2 += v * DW[(size_t)(t + 512) * N_DIM + col];
    }
  }
  a0 += db[t];
  a1 += db[t + 256];
  a2 += db[t + 512];
  float* xr = XR + (size_t)row * K_DIM;
  xr[t]       = a0;
  xr[t + 256] = a1;
  xr[t + 512] = a2;
}

// ---------------------------------------------------------------------------
extern "C" void kernel_launch(void* const* d_in, const int* in_sizes, int n_in,
                              void* d_out, int out_size, void* d_ws, size_t ws_size,
                              hipStream_t stream)
{
  (void)in_sizes; (void)n_in; (void)out_size;

  const float* x     = (const float*)d_in[0];
  const float* enc_w = (const float*)d_in[1];
  const float* enc_b = (const float*)d_in[2];
  const float* dec_w = (const float*)d_in[3];
  const float* dec_b = (const float*)d_in[4];
  // d_in[5] = k (constant 32, hardcoded as TOPK)

  float* out     = (float*)d_out;
  float* x_recon = out;                            // M*K floats
  float* z_sp    = out + (size_t)M_DIM * K_DIM;    // M*N floats

  const size_t wt_bytes = (size_t)N_DIM * K_DIM * sizeof(float);   // 37.75 MB
  const int use_wt = (ws_size >= wt_bytes) ? 1 : 0;                // fixed across calls
  float* WT = (float*)d_ws;

  if (use_wt) {
    dim3 tb(32, 8);
    dim3 tg(N_DIM / 32, K_DIM / 32);
    transpose_decw<<<tg, tb, 0, stream>>>(dec_w, WT);
  }

  {
    dim3 tb(16, 16);
    dim3 tg(N_DIM / 128, M_DIM / 128);   // (96, 128)
    TopKSparseAutoencoder_51917564674099_kernel<<<tg, tb, 0, stream>>>(x, enc_w, enc_b, z_sp);
  }

  topk_decode<<<M_DIM, 256, 0, stream>>>(z_sp, WT, dec_w, dec_b, x_recon, use_wt);
}